// Round 9
// baseline (267.783 us; speedup 1.0000x reference)
//
#include <hip/hip_runtime.h>
#include <hip/hip_fp16.h>

// GCN: N=50000 nodes, E=1.6M edges (+N self-loops), F_IN=11, H=128, G=1024, T=1.
// Pipeline (layer-3 folded into v3 = W3@Wl, c3 = b3 . Wl):
//   2D-binned counting-sort CSR build (bins = src-tile x dst-bucket)
//   -> lin1' = dinv*(x@W1) (fp16) -> h1 = relu(dinv*agg(lin1')+b1) (fp32)
//   -> lin2' = dinv*(h1@W2) (fp16) -> t'[n] = dinv*(relu(dinv*agg(lin2')+b2).v3)
//   -> s[n] = dinv*sum(t'[src]) + c3 -> segment-mean -> +bl
//
// R9 change: spmm is fill-bound (time ~ FETCH at ~3.7 TB/s across R3/R6/R7/R8;
// R8 pipeline raised VALUBusy 50->60% with no dur change). Working set 12.8MB
// vs 4MB L2/XCD -> ~31% hit rate (155MB fills vs 102MB compulsory). Fix: spans
// grouped by src-tile (7 tiles x 8192 rows = 2MB): 2D bins (tile,bucket),
// k_build scatters tile-region-by-region with syncthreads -> span content
// tile-ordered. Co-resident waves sweep src space in phases; hot band fits L2.
// spmm/pool unchanged (CSR permutation only; segment-sum is order-free).

constexpr int N_NODES = 50000;
constexpr int N_EDGES = 1600000;
constexpr int F_IN_C  = 11;
constexpr int HC      = 128;
constexpr int G_C     = 1024;
constexpr int NPB     = 128;                        // nodes per dst bucket
constexpr int NB      = (N_NODES + NPB - 1) / NPB;  // 391 dst buckets
constexpr int TSH     = 13;                         // src tile = src >> 13
constexpr int NT      = (N_NODES + (1 << TSH) - 1) >> TSH;  // 7 src tiles
constexpr int NBINS   = NT * NB;                    // 2737 bins
constexpr int CHUNK   = 8192;                       // edges per bin block
constexpr int NBLK_E  = (N_EDGES + CHUNK - 1) / CHUNK;
constexpr int ZROW    = N_NODES;                    // zero-row index for pads
constexpr int GM      = 32;                         // nodes per gemm block
constexpr int EPL     = (NBINS + 63) / 64;          // prefix elems per lane

// ---------------- fp16 pack/unpack ----------------

__device__ __forceinline__ unsigned pack_f16(float x, float y) {
  __half2 h = __floats2half2_rn(x, y);
  return *reinterpret_cast<unsigned*>(&h);
}

__device__ __forceinline__ float2 unpack_f16(unsigned u) {
  __half2 h = *reinterpret_cast<__half2*>(&u);
  return __half22float2(h);
}

// ---------------- CSR build (2D: src-tile x dst-bucket) ----------------

__device__ __forceinline__ int bin_of(int s, int d) {
  return (s >> TSH) * NB + (d >> 7);
}

// A1: bin histogram via per-block LDS counts.
__global__ __launch_bounds__(256) void k_bhist(const int* __restrict__ src,
                                               const int* __restrict__ dst,
                                               int* __restrict__ bcnt) {
  __shared__ int hist[NBINS];
  int t = threadIdx.x;
  for (int b = t; b < NBINS; b += 256) hist[b] = 0;
  __syncthreads();
  long e0 = (long)blockIdx.x * CHUNK;
  for (int it = 0; it < CHUNK / 1024; ++it) {
    long e = e0 + it * 1024 + t * 4;
    if (e < N_EDGES) {
      int4 s4 = *(const int4*)(src + e);
      int4 d4 = *(const int4*)(dst + e);
      atomicAdd(&hist[bin_of(s4.x, d4.x)], 1);
      atomicAdd(&hist[bin_of(s4.y, d4.y)], 1);
      atomicAdd(&hist[bin_of(s4.z, d4.z)], 1);
      atomicAdd(&hist[bin_of(s4.w, d4.w)], 1);
    }
  }
  __syncthreads();
  for (int b = t; b < NBINS; b += 256)
    if (hist[b]) atomicAdd(&bcnt[b], hist[b]);
}

// A2: exclusive prefix over 2737 bins. 1 block, 64 lanes, serial-per-lane.
__global__ __launch_bounds__(64) void k_prefix(const int* __restrict__ bcnt,
                                               int* __restrict__ bbase,
                                               int* __restrict__ bcur) {
  __shared__ int part[64];
  int l = threadIdx.x;
  int base = l * EPL;
  int s = 0;
  for (int i = 0; i < EPL; ++i)
    if (base + i < NBINS) s += bcnt[base + i];
  part[l] = s;
  __syncthreads();
  if (l == 0) {
    int acc = 0;
    for (int i = 0; i < 64; ++i) { int v = part[i]; part[i] = acc; acc += v; }
  }
  __syncthreads();
  int run = part[l];
  for (int i = 0; i < EPL; ++i) {
    if (base + i < NBINS) {
      bbase[base + i] = run;
      bcur[base + i]  = run;
      run += bcnt[base + i];
    }
  }
}

// A3: bin edges into 2D bin regions as packed records (src | dst_local<<16).
__global__ __launch_bounds__(256) void k_bin(const int* __restrict__ src,
                                             const int* __restrict__ dst,
                                             int* __restrict__ bcur,
                                             unsigned int* __restrict__ pairs) {
  __shared__ int hist[NBINS];
  __shared__ int curL[NBINS];
  int t = threadIdx.x;
  for (int b = t; b < NBINS; b += 256) hist[b] = 0;
  __syncthreads();
  long e0 = (long)blockIdx.x * CHUNK;
  for (int it = 0; it < CHUNK / 1024; ++it) {
    long e = e0 + it * 1024 + t * 4;
    if (e < N_EDGES) {
      int4 s4 = *(const int4*)(src + e);
      int4 d4 = *(const int4*)(dst + e);
      atomicAdd(&hist[bin_of(s4.x, d4.x)], 1);
      atomicAdd(&hist[bin_of(s4.y, d4.y)], 1);
      atomicAdd(&hist[bin_of(s4.z, d4.z)], 1);
      atomicAdd(&hist[bin_of(s4.w, d4.w)], 1);
    }
  }
  __syncthreads();
  for (int b = t; b < NBINS; b += 256)
    curL[b] = hist[b] ? atomicAdd(&bcur[b], hist[b]) : 0;  // absolute cursor
  __syncthreads();
  for (int it = 0; it < CHUNK / 1024; ++it) {
    long e = e0 + it * 1024 + t * 4;
    if (e < N_EDGES) {
      int4 s4 = *(const int4*)(src + e);
      int4 d4 = *(const int4*)(dst + e);
      {
        int p = atomicAdd(&curL[bin_of(s4.x, d4.x)], 1);
        pairs[p] = (unsigned)s4.x | ((unsigned)(d4.x & 127) << 16);
      }
      {
        int p = atomicAdd(&curL[bin_of(s4.y, d4.y)], 1);
        pairs[p] = (unsigned)s4.y | ((unsigned)(d4.y & 127) << 16);
      }
      {
        int p = atomicAdd(&curL[bin_of(s4.z, d4.z)], 1);
        pairs[p] = (unsigned)s4.z | ((unsigned)(d4.z & 127) << 16);
      }
      {
        int p = atomicAdd(&curL[bin_of(s4.w, d4.w)], 1);
        pairs[p] = (unsigned)s4.w | ((unsigned)(d4.w & 127) << 16);
      }
    }
  }
}

// B: per-bucket CSR build from NT tile regions, processed in tile order with
// a barrier between regions -> span content grouped by src tile.
// Spans padded to x8 with ZROW entries.
__global__ __launch_bounds__(256) void k_build(const unsigned int* __restrict__ pairs,
                                               const int* __restrict__ bbase,
                                               const int* __restrict__ bcur,
                                               int* __restrict__ total,
                                               int* __restrict__ start,
                                               int* __restrict__ deg,
                                               float* __restrict__ dinv,
                                               int* __restrict__ csr) {
  __shared__ int cntL[NPB], sc[NPB];
  __shared__ int csrBaseL;
  int t = threadIdx.x;
  int b = blockIdx.x;
  int nodeBase = b * NPB;
  int nib = min(NPB, N_NODES - nodeBase);
  if (t < NPB) cntL[t] = 0;
  __syncthreads();
  // count across all tile regions
  for (int r = 0; r < NT; ++r) {
    int pbase = bbase[r * NB + b];
    int size  = bcur[r * NB + b] - pbase;
    for (int p = t; p < size; p += 256)
      atomicAdd(&cntL[pairs[pbase + p] >> 16], 1);
  }
  __syncthreads();
  int d = 0, dpad = 0;
  if (t < NPB && t < nib) {
    d = cntL[t] + 1;                 // +1 self loop
    dpad = (d + 7) & ~7;             // span padded to multiple of 8
  }
  if (t < NPB) sc[t] = dpad;
  __syncthreads();
  for (int off = 1; off < NPB; off <<= 1) {
    int a = 0;
    if (t < NPB && t >= off) a = sc[t - off];
    __syncthreads();
    if (t < NPB) sc[t] += a;
    __syncthreads();
  }
  if (t == 0) csrBaseL = atomicAdd(total, sc[NPB - 1]);
  __syncthreads();
  int csrBase = csrBaseL;
  if (t < nib) {
    int excl = sc[t] - dpad;
    int n = nodeBase + t;
    int s = csrBase + excl;
    start[n] = s;
    deg[n]   = dpad;                 // spmm/pool iterate padded span
    dinv[n]  = rsqrtf((float)d);
    csr[s]   = n;                    // self-loop slot (first)
    for (int k = d; k < dpad; ++k) csr[s + k] = ZROW;  // zero-row pads (last)
    cntL[t]  = excl + 1;             // local cursor (after self loop)
  }
  __syncthreads();
  // scatter region-by-region: barrier between tiles keeps spans tile-ordered
  for (int r = 0; r < NT; ++r) {
    int pbase = bbase[r * NB + b];
    int size  = bcur[r * NB + b] - pbase;
    for (int p = t; p < size; p += 256) {
      unsigned v = pairs[pbase + p];
      int loc = atomicAdd(&cntL[v >> 16], 1);
      csr[csrBase + loc] = (int)(v & 0xFFFFu);
    }
    __syncthreads();
  }
}

// ---------------- dense pieces ----------------

// lin1' = dinv * (x @ W1), packed fp16. 4 nodes per 256-thread block.
__global__ __launch_bounds__(256) void k_lin1(const float* __restrict__ x,
                                              const float* __restrict__ W1,
                                              const float* __restrict__ dinv,
                                              unsigned* __restrict__ out) {
  __shared__ float w_s[F_IN_C * HC];
  for (int i = threadIdx.x; i < F_IN_C * HC; i += 256) w_s[i] = W1[i];
  __syncthreads();
  int lane = threadIdx.x & 63;
  int sub  = threadIdx.x >> 6;            // 4 nodes per block
  for (int n = blockIdx.x * 4 + sub; n < N_NODES; n += gridDim.x * 4) {
    const float* xr = x + (size_t)n * F_IN_C;
    float ax = 0.f, ay = 0.f;
#pragma unroll
    for (int k = 0; k < F_IN_C; ++k) {
      float xv = xr[k];
      ax += xv * w_s[k * HC + 2 * lane];
      ay += xv * w_s[k * HC + 2 * lane + 1];
    }
    float dn = dinv[n];
    out[(size_t)n * 64 + lane] = pack_f16(ax * dn, ay * dn);
  }
}

// lin2' = dinv * (h1 @ W2) (fp32 in, packed fp16 out). 32 nodes / 128 threads.
// Thread t: cols 4*(t&31)..+3, rows (t>>5)*8..+7. FMA:LDS = 4:1.
__global__ __launch_bounds__(128) void k_gemm(const float* __restrict__ in,
                                              const float* __restrict__ W,
                                              const float* __restrict__ dinv,
                                              unsigned* __restrict__ out) {
  __shared__ float in_s[GM][HC];
  int t  = threadIdx.x;
  int n0 = blockIdx.x * GM;
  int rows = min(GM, N_NODES - n0);
  const float4* inv4 = (const float4*)(in + (size_t)n0 * HC);
  float4* s4 = (float4*)&in_s[0][0];
  if (rows == GM) {
#pragma unroll
    for (int r = 0; r < 8; ++r) s4[t + r * 128] = inv4[t + r * 128];
  } else {
#pragma unroll
    for (int r = 0; r < 8; ++r) {
      int fv = t + r * 128;                    // float4 index; row = fv/32
      s4[fv] = (fv / 32 < rows) ? inv4[fv] : make_float4(0.f, 0.f, 0.f, 0.f);
    }
  }
  __syncthreads();
  int tp = t & 31;                             // col group (4 cols)
  int rg = t >> 5;                             // row group (8 rows)
  float a0[8], a1[8], a2[8], a3[8];
#pragma unroll
  for (int r = 0; r < 8; ++r) { a0[r] = 0.f; a1[r] = 0.f; a2[r] = 0.f; a3[r] = 0.f; }
  for (int k = 0; k < HC; ++k) {
    float4 w4 = *(const float4*)(W + k * HC + 4 * tp);
#pragma unroll
    for (int r = 0; r < 8; ++r) {
      float a = in_s[rg * 8 + r][k];           // half-wave-uniform broadcast
      a0[r] += a * w4.x;
      a1[r] += a * w4.y;
      a2[r] += a * w4.z;
      a3[r] += a * w4.w;
    }
  }
#pragma unroll
  for (int r = 0; r < 8; ++r) {
    int n = n0 + rg * 8 + r;
    if (n < N_NODES) {
      float dn = dinv[n];
      uint2 pk;
      pk.x = pack_f16(a0[r] * dn, a1[r] * dn);
      pk.y = pack_f16(a2[r] * dn, a3[r] * dn);
      *(uint2*)&out[(size_t)n * 64 + 2 * tp] = pk;
    }
  }
}

// v3 = W3 @ Wl (128), c3 = b3 . Wl. Also zeros pad rows / slots.
__global__ __launch_bounds__(128) void k_v3(const float* __restrict__ W3,
                                            const float* __restrict__ b3,
                                            const float* __restrict__ Wl,
                                            float* __restrict__ v3,
                                            float* __restrict__ c3,
                                            unsigned* __restrict__ lin1,
                                            unsigned* __restrict__ lin2,
                                            float* __restrict__ tbuf) {
  int k = threadIdx.x;
  float acc = 0.f;
  for (int j = 0; j < HC; ++j) acc += W3[k * HC + j] * Wl[j];
  v3[k] = acc;
  // zero-row init (row ZROW of lin1/lin2, tbuf[ZROW])
  if (k < 64) {
    lin1[(size_t)ZROW * 64 + k] = 0u;
    lin2[(size_t)ZROW * 64 + k] = 0u;
  }
  if (k == 64) tbuf[ZROW] = 0.f;
  __shared__ float red[128];
  red[k] = b3[k] * Wl[k];
  __syncthreads();
  for (int s = 64; s > 0; s >>= 1) {
    if (k < s) red[k] += red[k + s];
    __syncthreads();
  }
  if (k == 0) *c3 = red[0];
}

// ---------------- sparse aggregation ----------------

// Gathers prescaled packed-fp16 rows; csr via wave-uniform int4 loads.
// Software pipeline: csr 1 block ahead, gathers 1 block in flight.
// MODE 0: out[n][:] = relu(dinv[n]*agg + bias)       (float2/lane, fp32)
// MODE 1: out[n]    = dinv[n]*(relu(dinv[n]*agg + bias) . v3)  (scalar)
template <int MODE>
__global__ __launch_bounds__(256) void k_spmm(const unsigned* __restrict__ lin,
                                              const float* __restrict__ dinv,
                                              const int* __restrict__ start,
                                              const int* __restrict__ deg,
                                              const int* __restrict__ csr,
                                              const float* __restrict__ bias,
                                              const float* __restrict__ v3,
                                              float* __restrict__ out) {
  int wv = threadIdx.x >> 6, lane = threadIdx.x & 63;
  int n = blockIdx.x * 4 + wv;
  if (n >= N_NODES) return;
  int s0 = start[n], d = deg[n];          // multiple of 8, >= 8
  float dn = dinv[n];
  const unsigned* lp = lin + lane;        // per-lane gather base
  float ax[8], ay[8];
#pragma unroll
  for (int u = 0; u < 8; ++u) { ax[u] = 0.f; ay[u] = 0.f; }
  int nb = d >> 3;
  // prologue: csr block 0, gathers block 0, csr block 1
  int4 cc0 = *(const int4*)(csr + s0);
  int4 cc1 = *(const int4*)(csr + s0 + 4);
  unsigned qA[8];
  qA[0] = lp[(size_t)cc0.x * 64];
  qA[1] = lp[(size_t)cc0.y * 64];
  qA[2] = lp[(size_t)cc0.z * 64];
  qA[3] = lp[(size_t)cc0.w * 64];
  qA[4] = lp[(size_t)cc1.x * 64];
  qA[5] = lp[(size_t)cc1.y * 64];
  qA[6] = lp[(size_t)cc1.z * 64];
  qA[7] = lp[(size_t)cc1.w * 64];
  if (nb > 1) {
    cc0 = *(const int4*)(csr + s0 + 8);
    cc1 = *(const int4*)(csr + s0 + 12);
  }
  for (int b = 1; b < nb; ++b) {
    // issue gathers for block b (csr arrived during previous consume)
    unsigned qB[8];
    qB[0] = lp[(size_t)cc0.x * 64];
    qB[1] = lp[(size_t)cc0.y * 64];
    qB[2] = lp[(size_t)cc0.z * 64];
    qB[3] = lp[(size_t)cc0.w * 64];
    qB[4] = lp[(size_t)cc1.x * 64];
    qB[5] = lp[(size_t)cc1.y * 64];
    qB[6] = lp[(size_t)cc1.z * 64];
    qB[7] = lp[(size_t)cc1.w * 64];
    // prefetch csr for block b+1
    if (b + 1 < nb) {
      cc0 = *(const int4*)(csr + s0 + (b + 1) * 8);
      cc1 = *(const int4*)(csr + s0 + (b + 1) * 8 + 4);
    }
    // consume gathers of block b-1 (in flight for one full iteration)
#pragma unroll
    for (int u = 0; u < 8; ++u) {
      float2 v = unpack_f16(qA[u]);
      ax[u] += v.x;
      ay[u] += v.y;
    }
#pragma unroll
    for (int u = 0; u < 8; ++u) qA[u] = qB[u];
  }
  // epilogue: consume last block
#pragma unroll
  for (int u = 0; u < 8; ++u) {
    float2 v = unpack_f16(qA[u]);
    ax[u] += v.x;
    ay[u] += v.y;
  }
  float sx = ((ax[0] + ax[1]) + (ax[2] + ax[3])) + ((ax[4] + ax[5]) + (ax[6] + ax[7]));
  float sy = ((ay[0] + ay[1]) + (ay[2] + ay[3])) + ((ay[4] + ay[5]) + (ay[6] + ay[7]));
  sx = fmaxf(sx * dn + bias[lane * 2], 0.f);
  sy = fmaxf(sy * dn + bias[lane * 2 + 1], 0.f);
  if (MODE == 0) {
    ((float2*)out)[(size_t)n * 64 + lane] = make_float2(sx, sy);
  } else {
    float2 vv = ((const float2*)v3)[lane];
    float p = sx * vv.x + sy * vv.y;
#pragma unroll
    for (int o = 32; o > 0; o >>= 1) p += __shfl_down(p, o, 64);
    if (lane == 0) out[n] = p * dn;       // prescale for the pool pass
  }
}

// s[n] = dinv[n] * sum_e t'[src] + c3; segment-sum into graphs.
__global__ __launch_bounds__(256) void k_spmv_pool(const float* __restrict__ t,
                                                   const float* __restrict__ dinv,
                                                   const int* __restrict__ start,
                                                   const int* __restrict__ deg,
                                                   const int* __restrict__ csr,
                                                   const float* __restrict__ c3,
                                                   const int* __restrict__ batch,
                                                   float* __restrict__ ssum,
                                                   int* __restrict__ cntg) {
  int n = blockIdx.x * 256 + threadIdx.x;
  if (n >= N_NODES) return;
  int s0 = start[n], d = deg[n];          // padded span; t[ZROW]=0
  float a0 = 0.f, a1 = 0.f, a2 = 0.f, a3 = 0.f;
  for (int i = 0; i + 4 <= d; i += 4) {
    int4 c = *(const int4*)(csr + s0 + i);
    a0 += t[c.x];
    a1 += t[c.y];
    a2 += t[c.z];
    a3 += t[c.w];
  }
  float acc = ((a0 + a1) + (a2 + a3)) * dinv[n] + *c3;
  int g = batch[n];
  atomicAdd(&ssum[g], acc);
  atomicAdd(&cntg[g], 1);
}

__global__ __launch_bounds__(256) void k_out(const float* __restrict__ ssum,
                                             const int* __restrict__ cntg,
                                             const float* __restrict__ bl,
                                             float* __restrict__ out) {
  int g = blockIdx.x * 256 + threadIdx.x;
  if (g < G_C) out[g] = ssum[g] / fmaxf((float)cntg[g], 1.f) + bl[0];
}

// ---------------- launch ----------------

extern "C" void kernel_launch(void* const* d_in, const int* in_sizes, int n_in,
                              void* d_out, int out_size, void* d_ws, size_t ws_size,
                              hipStream_t stream) {
  const float* x     = (const float*)d_in[0];
  const int*   ei    = (const int*)d_in[1];
  const int*   srcE  = ei;
  const int*   dstE  = ei + N_EDGES;
  const int*   batch = (const int*)d_in[2];
  const float* W1 = (const float*)d_in[3];
  const float* b1 = (const float*)d_in[4];
  const float* W2 = (const float*)d_in[5];
  const float* b2 = (const float*)d_in[6];
  const float* W3 = (const float*)d_in[7];
  const float* b3 = (const float*)d_in[8];
  const float* Wl = (const float*)d_in[9];
  const float* bl = (const float*)d_in[10];
  float* out = (float*)d_out;

  // workspace layout (16B aligned slices)
  size_t off = 0;
  auto alloc = [&](size_t bytes) -> char* {
    char* p = (char*)d_ws + off;
    off = (off + bytes + 15) & ~(size_t)15;
    return p;
  };
  // bufA: pairs (6.4MB, CSR build) -> lin1' fp16 + lin2' fp16 ((N+1) rows each)
  char* bufA = alloc((size_t)(N_NODES + 1) * 2 * 256);     // 25.6 MB + 512B
  float* bufB = (float*)alloc((size_t)N_NODES * HC * 4);   // 25.6 MB (h1 fp32)
  unsigned* pairs = (unsigned*)bufA;
  unsigned* lin1  = (unsigned*)bufA;                       // (N+1)*64 uints
  unsigned* lin2  = (unsigned*)(bufA + (size_t)(N_NODES + 1) * 256);
  float* dinv = (float*)alloc((size_t)N_NODES * 4);
  float* tbuf = (float*)alloc((size_t)(N_NODES + 1) * 4);
  float* v3   = (float*)alloc(HC * 4);
  float* c3   = (float*)alloc(16);
  int* startA = (int*)alloc((size_t)N_NODES * 4);
  int* degA   = (int*)alloc((size_t)N_NODES * 4);
  // csr: padded spans (self-loop + edges + pad-to-8) <= E + 8*N
  int* csr    = (int*)alloc((size_t)(N_EDGES + 8 * N_NODES) * 4);  // 8.0 MB
  int* bbase  = (int*)alloc(NBINS * 4);
  int* bcur   = (int*)alloc(NBINS * 4);
  // zero zone: bcnt | total | ssum | cntg
  size_t zz_bytes = NBINS * 4 + 16 + G_C * 4 + G_C * 4;
  char* zz = alloc(zz_bytes);
  int*   bcnt = (int*)zz;
  int*   total= (int*)(zz + NBINS * 4);
  float* ssum = (float*)(zz + NBINS * 4 + 16);
  int*   cntg = (int*)(zz + NBINS * 4 + 16 + G_C * 4);

  hipMemsetAsync(zz, 0, zz_bytes, stream);

  k_bhist<<<NBLK_E, 256, 0, stream>>>(srcE, dstE, bcnt);
  k_prefix<<<1, 64, 0, stream>>>(bcnt, bbase, bcur);
  k_bin<<<NBLK_E, 256, 0, stream>>>(srcE, dstE, bcur, pairs);
  k_build<<<NB, 256, 0, stream>>>(pairs, bbase, bcur, total, startA, degA, dinv, csr);
  k_v3<<<1, 128, 0, stream>>>(W3, b3, Wl, v3, c3, lin1, lin2, tbuf);

  k_lin1<<<N_NODES / 4, 256, 0, stream>>>(x, W1, dinv, lin1);
  k_spmm<0><<<N_NODES / 4, 256, 0, stream>>>(lin1, dinv, startA, degA, csr, b1, v3, bufB);
  k_gemm<<<(N_NODES + GM - 1) / GM, 128, 0, stream>>>(bufB, W2, dinv, lin2);
  k_spmm<1><<<N_NODES / 4, 256, 0, stream>>>(lin2, dinv, startA, degA, csr, b2, v3, tbuf);
  k_spmv_pool<<<(N_NODES + 255) / 256, 256, 0, stream>>>(tbuf, dinv, startA, degA, csr,
                                                         c3, batch, ssum, cntg);
  k_out<<<(G_C + 255) / 256, 256, 0, stream>>>(ssum, cntg, bl, out);
}

// Round 10
// 238.357 us; speedup vs baseline: 1.1235x; 1.1235x over previous
//
#include <hip/hip_runtime.h>
#include <hip/hip_fp16.h>

// GCN: N=50000 nodes, E=1.6M edges (+N self-loops), F_IN=11, H=128, G=1024, T=1.
// Pipeline (layer-3 folded into v3 = W3@Wl, c3 = b3 . Wl):
//   binned counting-sort CSR build (A1 hist -> A2 prefix(+v3) -> A3 bin -> B)
//   -> lin1' = dinv*(x@W1) (fp16) -> h1 = relu(dinv*agg(lin1')+b1) (fp32)
//   -> lin2' = dinv*(h1@W2) (fp16) -> t'[n] = dinv*(relu(dinv*agg(lin2')+b2).v3)
//   -> s[n] = dinv*sum(t'[src]) + c3 -> segment-mean -> +bl
//
// R10: revert R9's 2D src-tile binning (FETCH unchanged 155MB, spmm unchanged
// ~50us, prep +27us -> locality-via-ordering refuted; spmm is fill-bound at
// ~3.7TB/s on the L2-miss path, 155MB vs ~102MB compulsory). Back to R8's 1D
// build; k_v3 fused into k_prefix (grid=2) to trim one launch from the fully
// serial chain.

constexpr int N_NODES = 50000;
constexpr int N_EDGES = 1600000;
constexpr int F_IN_C  = 11;
constexpr int HC      = 128;
constexpr int G_C     = 1024;
constexpr int NPB     = 128;                        // nodes per bucket
constexpr int NB      = (N_NODES + NPB - 1) / NPB;  // 391 buckets
constexpr int CHUNK   = 8192;                       // edges per bin block
constexpr int NBLK_E  = (N_EDGES + CHUNK - 1) / CHUNK;
constexpr int ZROW    = N_NODES;                    // zero-row index for pads
constexpr int GM      = 32;                         // nodes per gemm block

// ---------------- fp16 pack/unpack ----------------

__device__ __forceinline__ unsigned pack_f16(float x, float y) {
  __half2 h = __floats2half2_rn(x, y);
  return *reinterpret_cast<unsigned*>(&h);
}

__device__ __forceinline__ float2 unpack_f16(unsigned u) {
  __half2 h = *reinterpret_cast<__half2*>(&u);
  return __half22float2(h);
}

// ---------------- CSR build ----------------

// A1: bucket histogram via per-block LDS counts.
__global__ __launch_bounds__(256) void k_bhist(const int* __restrict__ dst,
                                               int* __restrict__ bcnt) {
  __shared__ int hist[NB];
  int t = threadIdx.x;
  for (int b = t; b < NB; b += 256) hist[b] = 0;
  __syncthreads();
  long e0 = (long)blockIdx.x * CHUNK;
  for (int it = 0; it < CHUNK / 1024; ++it) {
    long e = e0 + it * 1024 + t * 4;
    if (e < N_EDGES) {
      int4 d4 = *(const int4*)(dst + e);
      atomicAdd(&hist[d4.x >> 7], 1);
      atomicAdd(&hist[d4.y >> 7], 1);
      atomicAdd(&hist[d4.z >> 7], 1);
      atomicAdd(&hist[d4.w >> 7], 1);
    }
  }
  __syncthreads();
  for (int b = t; b < NB; b += 256)
    if (hist[b]) atomicAdd(&bcnt[b], hist[b]);
}

// A2 (block 0): exclusive prefix over bucket counts -> bucket base + cursor.
// (block 1): v3 = W3 @ Wl, c3 = b3 . Wl, zero-row init. Fused to cut a launch.
__global__ __launch_bounds__(512) void k_prefix_v3(const int* __restrict__ bcnt,
                                                   int* __restrict__ bbase,
                                                   int* __restrict__ bcur,
                                                   const float* __restrict__ W3,
                                                   const float* __restrict__ b3,
                                                   const float* __restrict__ Wl,
                                                   float* __restrict__ v3,
                                                   float* __restrict__ c3,
                                                   unsigned* __restrict__ lin1,
                                                   unsigned* __restrict__ lin2,
                                                   float* __restrict__ tbuf) {
  int t = threadIdx.x;
  if (blockIdx.x == 0) {
    __shared__ int sc[512];
    int v = (t < NB) ? bcnt[t] : 0;
    sc[t] = v;
    __syncthreads();
    for (int off = 1; off < 512; off <<= 1) {
      int a = (t >= off) ? sc[t - off] : 0;
      __syncthreads();
      sc[t] += a;
      __syncthreads();
    }
    if (t < NB) {
      int excl = sc[t] - v;
      bbase[t] = excl;
      bcur[t]  = excl;
    }
  } else {
    __shared__ float red[128];
    if (t < 128) {
      float acc = 0.f;
      for (int j = 0; j < HC; ++j) acc += W3[t * HC + j] * Wl[j];
      v3[t] = acc;
      if (t < 64) {
        lin1[(size_t)ZROW * 64 + t] = 0u;
        lin2[(size_t)ZROW * 64 + t] = 0u;
      }
      if (t == 64) tbuf[ZROW] = 0.f;
      red[t] = b3[t] * Wl[t];
    }
    __syncthreads();
    for (int s = 64; s > 0; s >>= 1) {
      if (t < s) red[t] += red[t + s];
      __syncthreads();
    }
    if (t == 0) *c3 = red[0];
  }
}

// A3: bin edges into bucket regions as packed records (src | dst_local<<16).
__global__ __launch_bounds__(256) void k_bin(const int* __restrict__ src,
                                             const int* __restrict__ dst,
                                             int* __restrict__ bcur,
                                             unsigned int* __restrict__ pairs) {
  __shared__ int hist[NB], base[NB], loff[NB];
  int t = threadIdx.x;
  for (int b = t; b < NB; b += 256) { hist[b] = 0; loff[b] = 0; }
  __syncthreads();
  long e0 = (long)blockIdx.x * CHUNK;
  for (int it = 0; it < CHUNK / 1024; ++it) {
    long e = e0 + it * 1024 + t * 4;
    if (e < N_EDGES) {
      int4 d4 = *(const int4*)(dst + e);
      atomicAdd(&hist[d4.x >> 7], 1);
      atomicAdd(&hist[d4.y >> 7], 1);
      atomicAdd(&hist[d4.z >> 7], 1);
      atomicAdd(&hist[d4.w >> 7], 1);
    }
  }
  __syncthreads();
  for (int b = t; b < NB; b += 256)
    if (hist[b]) base[b] = atomicAdd(&bcur[b], hist[b]);
  __syncthreads();
  for (int it = 0; it < CHUNK / 1024; ++it) {
    long e = e0 + it * 1024 + t * 4;
    if (e < N_EDGES) {
      int4 s4 = *(const int4*)(src + e);
      int4 d4 = *(const int4*)(dst + e);
      {
        int b = d4.x >> 7;
        int l = atomicAdd(&loff[b], 1);
        pairs[base[b] + l] = (unsigned)s4.x | ((unsigned)(d4.x & 127) << 16);
      }
      {
        int b = d4.y >> 7;
        int l = atomicAdd(&loff[b], 1);
        pairs[base[b] + l] = (unsigned)s4.y | ((unsigned)(d4.y & 127) << 16);
      }
      {
        int b = d4.z >> 7;
        int l = atomicAdd(&loff[b], 1);
        pairs[base[b] + l] = (unsigned)s4.z | ((unsigned)(d4.z & 127) << 16);
      }
      {
        int b = d4.w >> 7;
        int l = atomicAdd(&loff[b], 1);
        pairs[base[b] + l] = (unsigned)s4.w | ((unsigned)(d4.w & 127) << 16);
      }
    }
  }
}

// B: per-bucket CSR build. Spans padded to x8 with ZROW entries.
__global__ __launch_bounds__(256) void k_build(const unsigned int* __restrict__ pairs,
                                               const int* __restrict__ bbase,
                                               const int* __restrict__ bcur,
                                               int* __restrict__ total,
                                               int* __restrict__ start,
                                               int* __restrict__ deg,
                                               float* __restrict__ dinv,
                                               int* __restrict__ csr) {
  __shared__ int cntL[NPB], sc[NPB];
  __shared__ int csrBaseL;
  int t = threadIdx.x;
  int b = blockIdx.x;
  int nodeBase = b * NPB;
  int nib = min(NPB, N_NODES - nodeBase);
  int pbase = bbase[b];
  int pend  = bcur[b];         // after A3: base + size
  int size  = pend - pbase;
  if (t < NPB) cntL[t] = 0;
  __syncthreads();
  for (int p = t; p < size; p += 256)
    atomicAdd(&cntL[pairs[pbase + p] >> 16], 1);
  __syncthreads();
  int d = 0, dpad = 0;
  if (t < NPB && t < nib) {
    d = cntL[t] + 1;                 // +1 self loop
    dpad = (d + 7) & ~7;             // span padded to multiple of 8
  }
  if (t < NPB) sc[t] = dpad;
  __syncthreads();
  for (int off = 1; off < NPB; off <<= 1) {
    int a = 0;
    if (t < NPB && t >= off) a = sc[t - off];
    __syncthreads();
    if (t < NPB) sc[t] += a;
    __syncthreads();
  }
  if (t == 0) csrBaseL = atomicAdd(total, sc[NPB - 1]);
  __syncthreads();
  int csrBase = csrBaseL;
  if (t < nib) {
    int excl = sc[t] - dpad;
    int n = nodeBase + t;
    int s = csrBase + excl;
    start[n] = s;
    deg[n]   = dpad;                 // spmm/pool iterate padded span
    dinv[n]  = rsqrtf((float)d);
    csr[s]   = n;                    // self-loop slot
    for (int k = d; k < dpad; ++k) csr[s + k] = ZROW;  // zero-row pads
    cntL[t]  = excl + 1;             // local cursor (after self loop)
  }
  __syncthreads();
  for (int p = t; p < size; p += 256) {
    unsigned v = pairs[pbase + p];
    int loc = atomicAdd(&cntL[v >> 16], 1);
    csr[csrBase + loc] = (int)(v & 0xFFFFu);
  }
}

// ---------------- dense pieces ----------------

// lin1' = dinv * (x @ W1), packed fp16. 4 nodes per 256-thread block.
__global__ __launch_bounds__(256) void k_lin1(const float* __restrict__ x,
                                              const float* __restrict__ W1,
                                              const float* __restrict__ dinv,
                                              unsigned* __restrict__ out) {
  __shared__ float w_s[F_IN_C * HC];
  for (int i = threadIdx.x; i < F_IN_C * HC; i += 256) w_s[i] = W1[i];
  __syncthreads();
  int lane = threadIdx.x & 63;
  int sub  = threadIdx.x >> 6;            // 4 nodes per block
  for (int n = blockIdx.x * 4 + sub; n < N_NODES; n += gridDim.x * 4) {
    const float* xr = x + (size_t)n * F_IN_C;
    float ax = 0.f, ay = 0.f;
#pragma unroll
    for (int k = 0; k < F_IN_C; ++k) {
      float xv = xr[k];
      ax += xv * w_s[k * HC + 2 * lane];
      ay += xv * w_s[k * HC + 2 * lane + 1];
    }
    float dn = dinv[n];
    out[(size_t)n * 64 + lane] = pack_f16(ax * dn, ay * dn);
  }
}

// lin2' = dinv * (h1 @ W2) (fp32 in, packed fp16 out). 32 nodes / 128 threads.
// Thread t: cols 4*(t&31)..+3, rows (t>>5)*8..+7. FMA:LDS = 4:1.
__global__ __launch_bounds__(128) void k_gemm(const float* __restrict__ in,
                                              const float* __restrict__ W,
                                              const float* __restrict__ dinv,
                                              unsigned* __restrict__ out) {
  __shared__ float in_s[GM][HC];
  int t  = threadIdx.x;
  int n0 = blockIdx.x * GM;
  int rows = min(GM, N_NODES - n0);
  const float4* inv4 = (const float4*)(in + (size_t)n0 * HC);
  float4* s4 = (float4*)&in_s[0][0];
  if (rows == GM) {
#pragma unroll
    for (int r = 0; r < 8; ++r) s4[t + r * 128] = inv4[t + r * 128];
  } else {
#pragma unroll
    for (int r = 0; r < 8; ++r) {
      int fv = t + r * 128;                    // float4 index; row = fv/32
      s4[fv] = (fv / 32 < rows) ? inv4[fv] : make_float4(0.f, 0.f, 0.f, 0.f);
    }
  }
  __syncthreads();
  int tp = t & 31;                             // col group (4 cols)
  int rg = t >> 5;                             // row group (8 rows)
  float a0[8], a1[8], a2[8], a3[8];
#pragma unroll
  for (int r = 0; r < 8; ++r) { a0[r] = 0.f; a1[r] = 0.f; a2[r] = 0.f; a3[r] = 0.f; }
  for (int k = 0; k < HC; ++k) {
    float4 w4 = *(const float4*)(W + k * HC + 4 * tp);
#pragma unroll
    for (int r = 0; r < 8; ++r) {
      float a = in_s[rg * 8 + r][k];           // half-wave-uniform broadcast
      a0[r] += a * w4.x;
      a1[r] += a * w4.y;
      a2[r] += a * w4.z;
      a3[r] += a * w4.w;
    }
  }
#pragma unroll
  for (int r = 0; r < 8; ++r) {
    int n = n0 + rg * 8 + r;
    if (n < N_NODES) {
      float dn = dinv[n];
      uint2 pk;
      pk.x = pack_f16(a0[r] * dn, a1[r] * dn);
      pk.y = pack_f16(a2[r] * dn, a3[r] * dn);
      *(uint2*)&out[(size_t)n * 64 + 2 * tp] = pk;
    }
  }
}

// ---------------- sparse aggregation ----------------

// Gathers prescaled packed-fp16 rows; csr via wave-uniform int4 loads.
// Software pipeline: csr 1 block ahead, gathers 1 block in flight.
// MODE 0: out[n][:] = relu(dinv[n]*agg + bias)       (float2/lane, fp32)
// MODE 1: out[n]    = dinv[n]*(relu(dinv[n]*agg + bias) . v3)  (scalar)
template <int MODE>
__global__ __launch_bounds__(256) void k_spmm(const unsigned* __restrict__ lin,
                                              const float* __restrict__ dinv,
                                              const int* __restrict__ start,
                                              const int* __restrict__ deg,
                                              const int* __restrict__ csr,
                                              const float* __restrict__ bias,
                                              const float* __restrict__ v3,
                                              float* __restrict__ out) {
  int wv = threadIdx.x >> 6, lane = threadIdx.x & 63;
  int n = blockIdx.x * 4 + wv;
  if (n >= N_NODES) return;
  int s0 = start[n], d = deg[n];          // multiple of 8, >= 8
  float dn = dinv[n];
  const unsigned* lp = lin + lane;        // per-lane gather base
  float ax[8], ay[8];
#pragma unroll
  for (int u = 0; u < 8; ++u) { ax[u] = 0.f; ay[u] = 0.f; }
  int nb = d >> 3;
  // prologue: csr block 0, gathers block 0, csr block 1
  int4 cc0 = *(const int4*)(csr + s0);
  int4 cc1 = *(const int4*)(csr + s0 + 4);
  unsigned qA[8];
  qA[0] = lp[(size_t)cc0.x * 64];
  qA[1] = lp[(size_t)cc0.y * 64];
  qA[2] = lp[(size_t)cc0.z * 64];
  qA[3] = lp[(size_t)cc0.w * 64];
  qA[4] = lp[(size_t)cc1.x * 64];
  qA[5] = lp[(size_t)cc1.y * 64];
  qA[6] = lp[(size_t)cc1.z * 64];
  qA[7] = lp[(size_t)cc1.w * 64];
  if (nb > 1) {
    cc0 = *(const int4*)(csr + s0 + 8);
    cc1 = *(const int4*)(csr + s0 + 12);
  }
  for (int b = 1; b < nb; ++b) {
    // issue gathers for block b (csr arrived during previous consume)
    unsigned qB[8];
    qB[0] = lp[(size_t)cc0.x * 64];
    qB[1] = lp[(size_t)cc0.y * 64];
    qB[2] = lp[(size_t)cc0.z * 64];
    qB[3] = lp[(size_t)cc0.w * 64];
    qB[4] = lp[(size_t)cc1.x * 64];
    qB[5] = lp[(size_t)cc1.y * 64];
    qB[6] = lp[(size_t)cc1.z * 64];
    qB[7] = lp[(size_t)cc1.w * 64];
    // prefetch csr for block b+1
    if (b + 1 < nb) {
      cc0 = *(const int4*)(csr + s0 + (b + 1) * 8);
      cc1 = *(const int4*)(csr + s0 + (b + 1) * 8 + 4);
    }
    // consume gathers of block b-1 (in flight for one full iteration)
#pragma unroll
    for (int u = 0; u < 8; ++u) {
      float2 v = unpack_f16(qA[u]);
      ax[u] += v.x;
      ay[u] += v.y;
    }
#pragma unroll
    for (int u = 0; u < 8; ++u) qA[u] = qB[u];
  }
  // epilogue: consume last block
#pragma unroll
  for (int u = 0; u < 8; ++u) {
    float2 v = unpack_f16(qA[u]);
    ax[u] += v.x;
    ay[u] += v.y;
  }
  float sx = ((ax[0] + ax[1]) + (ax[2] + ax[3])) + ((ax[4] + ax[5]) + (ax[6] + ax[7]));
  float sy = ((ay[0] + ay[1]) + (ay[2] + ay[3])) + ((ay[4] + ay[5]) + (ay[6] + ay[7]));
  sx = fmaxf(sx * dn + bias[lane * 2], 0.f);
  sy = fmaxf(sy * dn + bias[lane * 2 + 1], 0.f);
  if (MODE == 0) {
    ((float2*)out)[(size_t)n * 64 + lane] = make_float2(sx, sy);
  } else {
    float2 vv = ((const float2*)v3)[lane];
    float p = sx * vv.x + sy * vv.y;
#pragma unroll
    for (int o = 32; o > 0; o >>= 1) p += __shfl_down(p, o, 64);
    if (lane == 0) out[n] = p * dn;       // prescale for the pool pass
  }
}

// s[n] = dinv[n] * sum_e t'[src] + c3; segment-sum into graphs.
__global__ __launch_bounds__(256) void k_spmv_pool(const float* __restrict__ t,
                                                   const float* __restrict__ dinv,
                                                   const int* __restrict__ start,
                                                   const int* __restrict__ deg,
                                                   const int* __restrict__ csr,
                                                   const float* __restrict__ c3,
                                                   const int* __restrict__ batch,
                                                   float* __restrict__ ssum,
                                                   int* __restrict__ cntg) {
  int n = blockIdx.x * 256 + threadIdx.x;
  if (n >= N_NODES) return;
  int s0 = start[n], d = deg[n];          // padded span; t[ZROW]=0
  float a0 = 0.f, a1 = 0.f, a2 = 0.f, a3 = 0.f;
  for (int i = 0; i + 4 <= d; i += 4) {
    int4 c = *(const int4*)(csr + s0 + i);
    a0 += t[c.x];
    a1 += t[c.y];
    a2 += t[c.z];
    a3 += t[c.w];
  }
  float acc = ((a0 + a1) + (a2 + a3)) * dinv[n] + *c3;
  int g = batch[n];
  atomicAdd(&ssum[g], acc);
  atomicAdd(&cntg[g], 1);
}

__global__ __launch_bounds__(256) void k_out(const float* __restrict__ ssum,
                                             const int* __restrict__ cntg,
                                             const float* __restrict__ bl,
                                             float* __restrict__ out) {
  int g = blockIdx.x * 256 + threadIdx.x;
  if (g < G_C) out[g] = ssum[g] / fmaxf((float)cntg[g], 1.f) + bl[0];
}

// ---------------- launch ----------------

extern "C" void kernel_launch(void* const* d_in, const int* in_sizes, int n_in,
                              void* d_out, int out_size, void* d_ws, size_t ws_size,
                              hipStream_t stream) {
  const float* x     = (const float*)d_in[0];
  const int*   ei    = (const int*)d_in[1];
  const int*   srcE  = ei;
  const int*   dstE  = ei + N_EDGES;
  const int*   batch = (const int*)d_in[2];
  const float* W1 = (const float*)d_in[3];
  const float* b1 = (const float*)d_in[4];
  const float* W2 = (const float*)d_in[5];
  const float* b2 = (const float*)d_in[6];
  const float* W3 = (const float*)d_in[7];
  const float* b3 = (const float*)d_in[8];
  const float* Wl = (const float*)d_in[9];
  const float* bl = (const float*)d_in[10];
  float* out = (float*)d_out;

  // workspace layout (16B aligned slices)
  size_t off = 0;
  auto alloc = [&](size_t bytes) -> char* {
    char* p = (char*)d_ws + off;
    off = (off + bytes + 15) & ~(size_t)15;
    return p;
  };
  // bufA: pairs (6.4MB, CSR build) -> lin1' fp16 + lin2' fp16 ((N+1) rows each)
  char* bufA = alloc((size_t)(N_NODES + 1) * 2 * 256);     // 25.6 MB + 512B
  float* bufB = (float*)alloc((size_t)N_NODES * HC * 4);   // 25.6 MB (h1 fp32)
  unsigned* pairs = (unsigned*)bufA;
  unsigned* lin1  = (unsigned*)bufA;                       // (N+1)*64 uints
  unsigned* lin2  = (unsigned*)(bufA + (size_t)(N_NODES + 1) * 256);
  float* dinv = (float*)alloc((size_t)N_NODES * 4);
  float* tbuf = (float*)alloc((size_t)(N_NODES + 1) * 4);
  float* v3   = (float*)alloc(HC * 4);
  float* c3   = (float*)alloc(16);
  int* startA = (int*)alloc((size_t)N_NODES * 4);
  int* degA   = (int*)alloc((size_t)N_NODES * 4);
  // csr: padded spans (self-loop + edges + pad-to-8) <= E + 8*N
  int* csr    = (int*)alloc((size_t)(N_EDGES + 8 * N_NODES) * 4);  // 8.0 MB
  int* bbase  = (int*)alloc(NB * 4);
  int* bcur   = (int*)alloc(NB * 4);
  // zero zone: bcnt | total | ssum | cntg
  size_t zz_bytes = NB * 4 + 16 + G_C * 4 + G_C * 4;
  char* zz = alloc(zz_bytes);
  int*   bcnt = (int*)zz;
  int*   total= (int*)(zz + NB * 4);
  float* ssum = (float*)(zz + NB * 4 + 16);
  int*   cntg = (int*)(zz + NB * 4 + 16 + G_C * 4);

  hipMemsetAsync(zz, 0, zz_bytes, stream);

  k_bhist<<<NBLK_E, 256, 0, stream>>>(dstE, bcnt);
  k_prefix_v3<<<2, 512, 0, stream>>>(bcnt, bbase, bcur, W3, b3, Wl, v3, c3,
                                     lin1, lin2, tbuf);
  k_bin<<<NBLK_E, 256, 0, stream>>>(srcE, dstE, bcur, pairs);
  k_build<<<NB, 256, 0, stream>>>(pairs, bbase, bcur, total, startA, degA, dinv, csr);

  k_lin1<<<N_NODES / 4, 256, 0, stream>>>(x, W1, dinv, lin1);
  k_spmm<0><<<N_NODES / 4, 256, 0, stream>>>(lin1, dinv, startA, degA, csr, b1, v3, bufB);
  k_gemm<<<(N_NODES + GM - 1) / GM, 128, 0, stream>>>(bufB, W2, dinv, lin2);
  k_spmm<1><<<N_NODES / 4, 256, 0, stream>>>(lin2, dinv, startA, degA, csr, b2, v3, tbuf);
  k_spmv_pool<<<(N_NODES + 255) / 256, 256, 0, stream>>>(tbuf, dinv, startA, degA, csr,
                                                         c3, batch, ssum, cntg);
  k_out<<<(G_C + 255) / 256, 256, 0, stream>>>(ssum, cntg, bl, out);
}